// Round 3
// baseline (63637.177 us; speedup 1.0000x reference)
//
#include <hip/hip_runtime.h>
#include <math.h>

// Problem constants (AttnDecoderRNN): H=1024 hidden, V=16000 vocab, B=64 batch,
// L=256 enc len, T=128 decoder steps.
#define HH 1024
#define VV 16000
#define BB 64
#define LL 256
#define TT 128

#define NBLK 256  // k_loop grid: one block per CU; all co-resident

// ---------------------------------------------------------------------------
// Workspace layout (floats):
//   H_all  [T][B][H]   : h_t for every step (feeds the big output GEMM)
//   xin    [B][2H]     : e | ctx   (input to comb GEMM)
//   x_acc  [B][H]      : comb GEMM result (pre-bias, pre-relu)
//   gates  [B][4H]     : FULLY pre-biased gate pre-activations
//   h_buf  [B][H]
//   c_buf  [B][H]      : cell state (single buffer: block b is sole owner)
//   bar    [2048 u32]  : software grid barrier state (memset 0 each launch)
//   encT   [B][L][H]   : optional transposed encoder (only if ws large enough)
// NO atomics anywhere: every output element has exactly one writer.
// ---------------------------------------------------------------------------

// Software grid barrier, multi-XCD safe (proven in round 2):
//  - agent-scope atomics (MALL coherence point)
//  - __threadfence() release/acquire around arrival/exit
//  - two-level arrival: 16 groups x 16 blocks, padded counters
__device__ __forceinline__ void grid_barrier(unsigned* bar)
{
    __syncthreads();
    if (threadIdx.x == 0) {
        __threadfence();  // release: push this block's writes to coherence pt
        unsigned* gen = bar;
        unsigned* gcnt = bar + 64 + (blockIdx.x >> 4) * 64;
        unsigned* root = bar + 1536;
        const unsigned g =
            __hip_atomic_load(gen, __ATOMIC_RELAXED, __HIP_MEMORY_SCOPE_AGENT);
        bool releaser = false;
        if (__hip_atomic_fetch_add(gcnt, 1u, __ATOMIC_ACQ_REL,
                                   __HIP_MEMORY_SCOPE_AGENT) == 15u) {
            __hip_atomic_store(gcnt, 0u, __ATOMIC_RELAXED,
                               __HIP_MEMORY_SCOPE_AGENT);
            if (__hip_atomic_fetch_add(root, 1u, __ATOMIC_ACQ_REL,
                                       __HIP_MEMORY_SCOPE_AGENT) == 15u) {
                __hip_atomic_store(root, 0u, __ATOMIC_RELAXED,
                                   __HIP_MEMORY_SCOPE_AGENT);
                __hip_atomic_store(gen, g + 1u, __ATOMIC_RELEASE,
                                   __HIP_MEMORY_SCOPE_AGENT);
                releaser = true;
            }
        }
        if (!releaser) {
            while (__hip_atomic_load(gen, __ATOMIC_ACQUIRE,
                                     __HIP_MEMORY_SCOPE_AGENT) == g)
                __builtin_amdgcn_s_sleep(1);
        }
        __threadfence();  // acquire: invalidate stale cached lines
    }
    __syncthreads();
}

__device__ __forceinline__ float sigm(float x) { return 1.0f / (1.0f + expf(-x)); }

// LSTM elementwise on PRE-BIASED gates (biases folded into gates GEMM).
// Block b is the sole owner of c_buf[b] -> single buffer, no race.
__device__ __forceinline__ void lstm_pb(
    const float* __restrict__ gates, float* __restrict__ c_buf,
    float* __restrict__ h_buf, float* __restrict__ Hall_t, float* h_s, int b,
    int tid, bool first_c)
{
    const int j = tid * 4;
    const float* gb = gates + (size_t)b * 4 * HH;
    float4 gi = *(const float4*)(gb + j);
    float4 gf = *(const float4*)(gb + HH + j);
    float4 gg = *(const float4*)(gb + 2 * HH + j);
    float4 go = *(const float4*)(gb + 3 * HH + j);
    float4 co = first_c ? make_float4(0.f, 0.f, 0.f, 0.f)
                        : *(const float4*)(c_buf + (size_t)b * HH + j);
    float4 cn, hn;
#define DO_LSTM(X)                                \
    {                                             \
        float iv = sigm(gi.X);                    \
        float fv = sigm(gf.X);                    \
        float gv = tanhf(gg.X);                   \
        float ov = sigm(go.X);                    \
        float c2 = fv * co.X + iv * gv;           \
        cn.X = c2;                                \
        hn.X = ov * tanhf(c2);                    \
    }
    DO_LSTM(x) DO_LSTM(y) DO_LSTM(z) DO_LSTM(w)
#undef DO_LSTM
    *(float4*)(c_buf + (size_t)b * HH + j) = cn;
    *(float4*)(h_buf + (size_t)b * HH + j) = hn;
    *(float4*)(Hall_t + (size_t)b * HH + j) = hn;
    if (h_s) *(float4*)(h_s + j) = hn;
}

// ---------------------------------------------------------------------------
// gemm_rowtile: OUT[64][NW] over cols n0..n0+NW = A[64][K] @ W[n0..][K]^T.
// 256 threads. lane = output row; 4 waves split K 4-ways (independent LDS
// chunks, NO cross-wave sync in the main loop); final LDS reduce across waves.
// RELU: A element -> relu(A+abias). OUTMODE: 0 store, 1 store+bias1+bias2,
// 2 read-modify-write add (sole writer, plain ops — NO atomics).
// ---------------------------------------------------------------------------
template <int NW, bool RELU, int OUTMODE>
__device__ __forceinline__ void gemm_rowtile(
    const float* __restrict__ A, int lda, const float* __restrict__ abias,
    const float* __restrict__ Wm, int ldw, int n0, int klen,
    const float* __restrict__ bias1, const float* __restrict__ bias2,
    float* __restrict__ outp, int ldo, float* __restrict__ smem)
{
    static_assert(NW % 8 == 0, "NW multiple of 8");
    constexpr int NWP = NW + 4;  // 16B-aligned row stride for Ws
    const int tid = threadIdx.x;
    const int wv = tid >> 6, lane = tid & 63;
    const int kw = klen >> 2;        // per-wave K extent
    const int kbase = wv * kw;
    const int nch = kw >> 5;         // 32-wide chunks
    float* Asw = smem + wv * (64 * 33);                    // [64][33] per wave
    float* Wsw = smem + 4 * 64 * 33 + wv * (32 * NWP);     // [32][NWP] per wave
    const int arow = lane >> 3, ac4 = lane & 7;
    float acc[NW];
#pragma unroll
    for (int j = 0; j < NW; ++j) acc[j] = 0.f;

    float4 pa[8];
    float4 pw[NW / 8];
    {
        const int kk = kbase + ac4 * 4;
#pragma unroll
        for (int i = 0; i < 8; ++i)
            pa[i] = *(const float4*)(A + (size_t)(i * 8 + arow) * lda + kk);
#pragma unroll
        for (int i = 0; i < NW / 8; ++i)
            pw[i] = *(const float4*)(Wm + (size_t)(n0 + i * 8 + arow) * ldw + kk);
    }
    for (int ch = 0; ch < nch; ++ch) {
        const int kk = kbase + ch * 32;
        float4 bv;
        if (RELU) bv = *(const float4*)(abias + kk + ac4 * 4);
#pragma unroll
        for (int i = 0; i < 8; ++i) {
            float4 v = pa[i];
            if (RELU) {
                v.x = fmaxf(v.x + bv.x, 0.f); v.y = fmaxf(v.y + bv.y, 0.f);
                v.z = fmaxf(v.z + bv.z, 0.f); v.w = fmaxf(v.w + bv.w, 0.f);
            }
            const int base = (i * 8 + arow) * 33 + ac4 * 4;
            Asw[base + 0] = v.x; Asw[base + 1] = v.y;
            Asw[base + 2] = v.z; Asw[base + 3] = v.w;
        }
#pragma unroll
        for (int i = 0; i < NW / 8; ++i) {
            const int r = i * 8 + arow;
            Wsw[(ac4 * 4 + 0) * NWP + r] = pw[i].x;
            Wsw[(ac4 * 4 + 1) * NWP + r] = pw[i].y;
            Wsw[(ac4 * 4 + 2) * NWP + r] = pw[i].z;
            Wsw[(ac4 * 4 + 3) * NWP + r] = pw[i].w;
        }
        if (ch + 1 < nch) {  // register prefetch of next chunk
            const int k2 = kbase + (ch + 1) * 32 + ac4 * 4;
#pragma unroll
            for (int i = 0; i < 8; ++i)
                pa[i] = *(const float4*)(A + (size_t)(i * 8 + arow) * lda + k2);
#pragma unroll
            for (int i = 0; i < NW / 8; ++i)
                pw[i] = *(const float4*)(Wm + (size_t)(n0 + i * 8 + arow) * ldw + k2);
        }
#pragma unroll
        for (int k = 0; k < 32; ++k) {
            const float a = Asw[lane * 33 + k];  // bank = (lane+k)%32: conflict-free
#pragma unroll
            for (int j4 = 0; j4 < NW / 4; ++j4) {
                const float4 w4 = *(const float4*)&Wsw[k * NWP + j4 * 4];  // broadcast
                acc[j4 * 4 + 0] += a * w4.x;
                acc[j4 * 4 + 1] += a * w4.y;
                acc[j4 * 4 + 2] += a * w4.z;
                acc[j4 * 4 + 3] += a * w4.w;
            }
        }
    }
    // cross-wave reduce (red aliases As region: sync before overwrite)
    __syncthreads();
    float* red = smem;  // [4][64][NW]
#pragma unroll
    for (int j4 = 0; j4 < NW / 4; ++j4)
        *(float4*)&red[((wv * 64 + lane) * NW) + j4 * 4] = make_float4(
            acc[j4 * 4 + 0], acc[j4 * 4 + 1], acc[j4 * 4 + 2], acc[j4 * 4 + 3]);
    __syncthreads();
    constexpr int P = NW / 4;
    const int row = tid >> 2, jg = (tid & 3) * P;
#pragma unroll
    for (int p = 0; p < P; ++p) {
        const int j = jg + p;
        float v = red[(0 * 64 + row) * NW + j] + red[(1 * 64 + row) * NW + j] +
                  red[(2 * 64 + row) * NW + j] + red[(3 * 64 + row) * NW + j];
        if (OUTMODE == 1) v += bias1[n0 + j] + bias2[n0 + j];
        if (OUTMODE == 2)
            outp[(size_t)row * ldo + n0 + j] += v;
        else
            outp[(size_t)row * ldo + n0 + j] = v;
    }
    __syncthreads();  // protect smem before next phase reuses it
}

// ---------------------------------------------------------------------------
// k_loop: 128-step recurrence, 3 grid barriers per step, ZERO atomics.
// Phase A (blocks 0..63, one per b): LSTM(t-1) + scores + softmax + ctx.
// Phase B: blocks 0..127 comb (x_acc = xin@Wcomb^T, NW=8);
//          blocks 128..255 gates = h@Whh^T + b_ih + b_hh (NW=32).
// Phase C: all 256 blocks: gates += relu(x_acc+b_comb)@Wih^T (NW=16, RMW).
// ---------------------------------------------------------------------------
__global__ __launch_bounds__(256) void k_loop(
    const int* __restrict__ tok_all, const float* __restrict__ enc,
    const float* __restrict__ encT, const float* __restrict__ emb,
    const float* __restrict__ Wattn, const float* __restrict__ battn,
    const float* __restrict__ Wcomb, const float* __restrict__ bcomb,
    const float* __restrict__ Wih, const float* __restrict__ Whh,
    const float* __restrict__ b_ih, const float* __restrict__ b_hh,
    float* __restrict__ Hall, float* __restrict__ xin,
    float* __restrict__ x_acc, float* __restrict__ gates,
    float* __restrict__ h_buf, float* __restrict__ c_buf,
    unsigned* __restrict__ bar, int use_t)
{
    __shared__ __align__(16) float smem[4 * 64 * 33 + 4 * 32 * 36];  // 52.2 KB
    const int bid = blockIdx.x;
    const int tid = threadIdx.x;
    const int w = tid >> 6, lane = tid & 63;

    const int is64 = (tok_all[1] == 0 && tok_all[3] == 0 && tok_all[5] == 0 &&
                      tok_all[7] == 0);

    for (int t = 0; t < TT; ++t) {
        // ================= Phase A: per-b LSTM + attention =================
        if (bid < BB) {
            const int b = bid;
            float* e_s = smem;                 // [1024]
            float* h_s = smem + HH;            // [1024]
            float* sc = smem + 2 * HH;         // [256]
            float* red = smem + 2 * HH + LL;   // [8]

            const int tok = is64 ? tok_all[2 * (b * TT + t)] : tok_all[b * TT + t];
            float4 ev = ((const float4*)(emb + (size_t)tok * HH))[tid];
            ((float4*)e_s)[tid] = ev;
            ((float4*)(xin + (size_t)b * 2 * HH))[tid] = ev;

            if (t == 0) {
                float4 hv = ((const float4*)(enc + (size_t)(LL - 1) * BB * HH +
                                             (size_t)b * HH))[tid];
                ((float4*)h_s)[tid] = hv;
                ((float4*)(h_buf + (size_t)b * HH))[tid] = hv;
            } else {
                lstm_pb(gates, c_buf, h_buf, Hall + (size_t)(t - 1) * BB * HH,
                        h_s, b, tid, t == 1);
            }
            __syncthreads();

            // scores: wave w handles l in [w*64, w*64+64)
            const float4* es4 = (const float4*)e_s;
            const float4* hs4 = (const float4*)h_s;
            for (int li = 0; li < 64; ++li) {
                const int l = w * 64 + li;
                const float4* wr = (const float4*)(Wattn + (size_t)l * 2 * HH);
                float a = 0.f;
#pragma unroll
                for (int it = 0; it < 4; ++it) {
                    float4 wv = wr[it * 64 + lane];
                    float4 xv = es4[it * 64 + lane];
                    a += wv.x * xv.x + wv.y * xv.y + wv.z * xv.z + wv.w * xv.w;
                }
#pragma unroll
                for (int it = 0; it < 4; ++it) {
                    float4 wv = wr[256 + it * 64 + lane];
                    float4 xv = hs4[it * 64 + lane];
                    a += wv.x * xv.x + wv.y * xv.y + wv.z * xv.z + wv.w * xv.w;
                }
#pragma unroll
                for (int o = 32; o > 0; o >>= 1) a += __shfl_down(a, o, 64);
                if (lane == 0) sc[l] = a + battn[l];
            }
            __syncthreads();

            // softmax over sc[0..255] (one element per thread)
            const float sv = sc[tid];
            float m = sv;
#pragma unroll
            for (int o = 32; o > 0; o >>= 1) m = fmaxf(m, __shfl_down(m, o, 64));
            if (lane == 0) red[w] = m;
            __syncthreads();
            m = fmaxf(fmaxf(red[0], red[1]), fmaxf(red[2], red[3]));
            const float ex = expf(sv - m);
            float s = ex;
#pragma unroll
            for (int o = 32; o > 0; o >>= 1) s += __shfl_down(s, o, 64);
            if (lane == 0) red[4 + w] = s;
            __syncthreads();
            const float tot = red[4] + red[5] + red[6] + red[7];
            sc[tid] = ex / tot;
            __syncthreads();

            // ctx[b][4*tid..] = sum_l aw[l] * enc[l][b][...]
            float4 ctx = make_float4(0.f, 0.f, 0.f, 0.f);
            const float4* ebase;
            size_t lstr;
            if (use_t) {  // contiguous per-b stream [b][l][h]
                ebase = (const float4*)(encT + (size_t)b * LL * HH) + tid;
                lstr = HH / 4;
            } else {
                ebase = (const float4*)(enc + (size_t)b * HH) + tid;
                lstr = (size_t)BB * HH / 4;
            }
#pragma unroll 8
            for (int l = 0; l < LL; ++l) {
                const float a = sc[l];
                float4 e2 = ebase[(size_t)l * lstr];
                ctx.x += a * e2.x; ctx.y += a * e2.y;
                ctx.z += a * e2.z; ctx.w += a * e2.w;
            }
            ((float4*)(xin + (size_t)b * 2 * HH + HH))[tid] = ctx;
        }
        grid_barrier(bar);

        // ================= Phase B: comb || h@Whh^T ========================
        if (bid < 128) {
            gemm_rowtile<8, false, 0>(xin, 2 * HH, nullptr, Wcomb, 2 * HH,
                                      bid * 8, 2 * HH, nullptr, nullptr, x_acc,
                                      HH, smem);
        } else {
            gemm_rowtile<32, false, 1>(h_buf, HH, nullptr, Whh, HH,
                                       (bid - 128) * 32, HH, b_ih, b_hh, gates,
                                       4 * HH, smem);
        }
        grid_barrier(bar);

        // ================= Phase C: gates += relu(x+b)@Wih^T ===============
        gemm_rowtile<16, true, 2>(x_acc, HH, bcomb, Wih, HH, bid * 16, HH,
                                  nullptr, nullptr, gates, 4 * HH, smem);
        grid_barrier(bar);
    }

    // ================= Epilogue: final LSTM -> Hall[T-1] ===================
    if (bid < BB) {
        lstm_pb(gates, c_buf, h_buf, Hall + (size_t)(TT - 1) * BB * HH, nullptr,
                bid, tid, false);
    }
}

// ---------------------------------------------------------------------------
// k_tr: one-time enc [L][B][H] -> encT [B][L][H] (both sides coalesced).
// ---------------------------------------------------------------------------
__global__ __launch_bounds__(256) void k_tr(const float* __restrict__ enc,
                                            float* __restrict__ encT)
{
    const size_t idx = (size_t)blockIdx.x * 256 + threadIdx.x;  // float4 index
    const int h4 = idx & 255;
    const size_t lb = idx >> 8;
    const int b = lb & 63;
    const int l = (int)(lb >> 6);
    ((float4*)encT)[(((size_t)b * LL + l) * (HH / 4)) + h4] =
        ((const float4*)enc)[idx];
}

// ---------------------------------------------------------------------------
// k_out: out[t,b,v] = logits - LSE over b (log_softmax over BATCH axis).
// Unchanged (proven). b_out cancels in log-softmax over batch.
// ---------------------------------------------------------------------------
__global__ __launch_bounds__(256) void k_out(const float* __restrict__ Hall,
                                             const float* __restrict__ Wout,
                                             float* __restrict__ out)
{
    const int t = blockIdx.y;
    const int n0 = blockIdx.x * 128;
    const float* A = Hall + (size_t)t * BB * HH;
    __shared__ float As[32][68];
    __shared__ float Ws[32][132];
    __shared__ float Cs[64][129];
    __shared__ float lse_s[128];
    const int tid = threadIdx.x;
    const int ty = tid >> 4, tx = tid & 15;
    const int q = tid & 7, r = tid >> 3;
    float acc[4][8] = {};

    float4 pa0, pa1, pw0, pw1, pw2, pw3;
    {
        const int kk = q * 4;
        pa0 = *(const float4*)(A + (size_t)r * HH + kk);
        pa1 = *(const float4*)(A + (size_t)(r + 32) * HH + kk);
        pw0 = *(const float4*)(Wout + (size_t)(n0 + r) * HH + kk);
        pw1 = *(const float4*)(Wout + (size_t)(n0 + r + 32) * HH + kk);
        pw2 = *(const float4*)(Wout + (size_t)(n0 + r + 64) * HH + kk);
        pw3 = *(const float4*)(Wout + (size_t)(n0 + r + 96) * HH + kk);
    }
    for (int kc = 0; kc < HH; kc += 32) {
        As[q * 4 + 0][r] = pa0.x; As[q * 4 + 1][r] = pa0.y;
        As[q * 4 + 2][r] = pa0.z; As[q * 4 + 3][r] = pa0.w;
        As[q * 4 + 0][r + 32] = pa1.x; As[q * 4 + 1][r + 32] = pa1.y;
        As[q * 4 + 2][r + 32] = pa1.z; As[q * 4 + 3][r + 32] = pa1.w;
        Ws[q * 4 + 0][r] = pw0.x; Ws[q * 4 + 1][r] = pw0.y;
        Ws[q * 4 + 2][r] = pw0.z; Ws[q * 4 + 3][r] = pw0.w;
        Ws[q * 4 + 0][r + 32] = pw1.x; Ws[q * 4 + 1][r + 32] = pw1.y;
        Ws[q * 4 + 2][r + 32] = pw1.z; Ws[q * 4 + 3][r + 32] = pw1.w;
        Ws[q * 4 + 0][r + 64] = pw2.x; Ws[q * 4 + 1][r + 64] = pw2.y;
        Ws[q * 4 + 2][r + 64] = pw2.z; Ws[q * 4 + 3][r + 64] = pw2.w;
        Ws[q * 4 + 0][r + 96] = pw3.x; Ws[q * 4 + 1][r + 96] = pw3.y;
        Ws[q * 4 + 2][r + 96] = pw3.z; Ws[q * 4 + 3][r + 96] = pw3.w;
        __syncthreads();
        if (kc + 32 < HH) {
            const int kk = kc + 32 + q * 4;
            pa0 = *(const float4*)(A + (size_t)r * HH + kk);
            pa1 = *(const float4*)(A + (size_t)(r + 32) * HH + kk);
            pw0 = *(const float4*)(Wout + (size_t)(n0 + r) * HH + kk);
            pw1 = *(const float4*)(Wout + (size_t)(n0 + r + 32) * HH + kk);
            pw2 = *(const float4*)(Wout + (size_t)(n0 + r + 64) * HH + kk);
            pw3 = *(const float4*)(Wout + (size_t)(n0 + r + 96) * HH + kk);
        }
#pragma unroll
        for (int k = 0; k < 32; ++k) {
            const float4 a = *(const float4*)&As[k][ty * 4];
            const float4 w0 = *(const float4*)&Ws[k][tx * 8];
            const float4 w1 = *(const float4*)&Ws[k][tx * 8 + 4];
            const float av[4] = {a.x, a.y, a.z, a.w};
            const float bv[8] = {w0.x, w0.y, w0.z, w0.w, w1.x, w1.y, w1.z, w1.w};
#pragma unroll
            for (int i = 0; i < 4; ++i)
#pragma unroll
                for (int j = 0; j < 8; ++j) acc[i][j] += av[i] * bv[j];
        }
        __syncthreads();
    }
#pragma unroll
    for (int i = 0; i < 4; ++i)
#pragma unroll
        for (int j = 0; j < 8; ++j) Cs[ty * 4 + i][tx * 8 + j] = acc[i][j];
    __syncthreads();

    if (tid < 128) {
        float m = -1e30f;
        for (int b = 0; b < 64; ++b) m = fmaxf(m, Cs[b][tid]);
        float s = 0.f;
        for (int b = 0; b < 64; ++b) s += expf(Cs[b][tid] - m);
        lse_s[tid] = m + logf(s);
    }
    __syncthreads();

    const int col = tid & 127, bh = tid >> 7;
    float* outp = out + (size_t)t * BB * VV + n0 + col;
    for (int b = bh; b < 64; b += 2)
        outp[(size_t)b * VV] = Cs[b][col] - lse_s[col];
}

// ---------------------------------------------------------------------------
extern "C" void kernel_launch(void* const* d_in, const int* in_sizes, int n_in,
                              void* d_out, int out_size, void* d_ws, size_t ws_size,
                              hipStream_t stream)
{
    const int* tok = (const int*)d_in[0];
    const float* enc = (const float*)d_in[1];
    const float* emb = (const float*)d_in[2];
    const float* W_attn = (const float*)d_in[3];
    const float* b_attn = (const float*)d_in[4];
    const float* W_comb = (const float*)d_in[5];
    const float* b_comb = (const float*)d_in[6];
    const float* W_ih = (const float*)d_in[7];
    const float* W_hh = (const float*)d_in[8];
    const float* b_ih = (const float*)d_in[9];
    const float* b_hh = (const float*)d_in[10];
    const float* W_out = (const float*)d_in[11];
    // d_in[12] = b_out: cancels in log_softmax(axis=batch)
    float* out = (float*)d_out;
    float* ws = (float*)d_ws;

    const size_t n_Hall = (size_t)TT * BB * HH;   // 8388608
    const size_t n_xin = (size_t)BB * 2 * HH;     // 131072
    const size_t n_xacc = (size_t)BB * HH;        // 65536
    const size_t n_gates = (size_t)BB * 4 * HH;   // 262144
    const size_t n_bh = (size_t)BB * HH;          // h, c
    const size_t n_bar = 2048;
    const size_t n_encT = (size_t)BB * LL * HH;   // 16777216 (optional)
    const size_t base =
        n_Hall + n_xin + n_xacc + n_gates + 2 * n_bh + n_bar;
    if (ws_size < base * 4) return;  // would corrupt; bail
    const int use_t = (ws_size >= (base + n_encT) * 4) ? 1 : 0;

    float* H_all = ws;
    float* xin = H_all + n_Hall;
    float* x_acc = xin + n_xin;
    float* gates = x_acc + n_xacc;
    float* h_buf = gates + n_gates;
    float* c_buf = h_buf + n_bh;
    unsigned* bar = (unsigned*)(c_buf + n_bh);
    float* encT = (float*)(bar + n_bar);

    hipMemsetAsync(bar, 0, n_bar * 4, stream);
    if (use_t)
        k_tr<<<(LL * BB * HH / 4) / 256, 256, 0, stream>>>(enc, encT);

    k_loop<<<NBLK, 256, 0, stream>>>(tok, enc, encT, emb, W_attn, b_attn,
                                     W_comb, b_comb, W_ih, W_hh, b_ih, b_hh,
                                     H_all, xin, x_acc, gates, h_buf, c_buf,
                                     bar, use_t);
    k_out<<<dim3(125, 128), 256, 0, stream>>>(H_all, W_out, out);
}

// Round 4
// 52135.327 us; speedup vs baseline: 1.2206x; 1.2206x over previous
//
#include <hip/hip_runtime.h>
#include <math.h>

// Problem constants (AttnDecoderRNN): H=1024 hidden, V=16000 vocab, B=64 batch,
// L=256 enc len, T=128 decoder steps.
#define HH 1024
#define VV 16000
#define BB 64
#define LL 256
#define TT 128

#define NBLK 256  // k_loop grid: one block per CU; all co-resident

// ---------------------------------------------------------------------------
// Workspace layout (floats):
//   H_all  [T][B][H]   : h_t for every step (feeds the big output GEMM)
//   xin    [B][2H]     : e | ctx   (input to comb GEMM)
//   x_acc  [B][H]      : comb GEMM result (pre-bias, pre-relu)
//   gates  [B][4H]     : FULLY pre-biased gate pre-activations
//   h_buf  [B][H]
//   c0,c1  [B][H]      : double-buffered cell state (sibling blocks recompute
//                        LSTM reading old c while hq==0 writes new c)
//   bar    [2048 u32]  : software grid barrier state (memset 0 each launch)
//   encT   [B][L][H]   : optional transposed encoder (only if ws large enough)
// NO atomics in data path: every output element has exactly one writer.
// ---------------------------------------------------------------------------

// Software grid barrier v2, multi-XCD safe:
//  - agent-scope atomics (MALL coherence point)
//  - __threadfence() release/acquire around arrival/exit
//  - two-level arrival: 16 groups x 16 blocks, 64B-padded counters
//  - DISTRIBUTED release: 16 per-group release lines (vs 1 hot line) and
//    s_sleep(8) backoff -> spinners can't DoS the coherence point while
//    other blocks work (round-3 failure mode).
__device__ __forceinline__ void grid_barrier(unsigned* bar)
{
    __syncthreads();
    if (threadIdx.x == 0) {
        __threadfence();  // release: push this block's writes to coherence pt
        const int grp = blockIdx.x >> 4;
        unsigned* gcnt = bar + 64 + grp * 16;   // 64B-padded group counters
        unsigned* root = bar + 32;
        unsigned* grel = bar + 512 + grp * 16;  // 64B-padded per-group release
        const unsigned g =
            __hip_atomic_load(grel, __ATOMIC_RELAXED, __HIP_MEMORY_SCOPE_AGENT);
        if (__hip_atomic_fetch_add(gcnt, 1u, __ATOMIC_ACQ_REL,
                                   __HIP_MEMORY_SCOPE_AGENT) == 15u) {
            __hip_atomic_store(gcnt, 0u, __ATOMIC_RELAXED,
                               __HIP_MEMORY_SCOPE_AGENT);
            if (__hip_atomic_fetch_add(root, 1u, __ATOMIC_ACQ_REL,
                                       __HIP_MEMORY_SCOPE_AGENT) == 15u) {
                __hip_atomic_store(root, 0u, __ATOMIC_RELAXED,
                                   __HIP_MEMORY_SCOPE_AGENT);
#pragma unroll
                for (int i = 0; i < 16; ++i)
                    __hip_atomic_store(bar + 512 + i * 16, g + 1u,
                                       __ATOMIC_RELEASE,
                                       __HIP_MEMORY_SCOPE_AGENT);
            }
        }
        while (__hip_atomic_load(grel, __ATOMIC_ACQUIRE,
                                 __HIP_MEMORY_SCOPE_AGENT) == g)
            __builtin_amdgcn_s_sleep(8);
        __threadfence();  // acquire: invalidate stale cached lines
    }
    __syncthreads();
}

__device__ __forceinline__ float sigm(float x) { return 1.0f / (1.0f + expf(-x)); }

// LSTM elementwise on PRE-BIASED gates. All sibling blocks compute the same
// result (reading old c from c_rd); only `writer` stores globals (to c_wr).
__device__ __forceinline__ void lstm_pb(
    const float* __restrict__ gates, const float* __restrict__ c_rd,
    float* __restrict__ c_wr, float* __restrict__ h_buf,
    float* __restrict__ Hall_t, float* h_s, int b, int tid, bool first_c,
    bool writer)
{
    const int j = tid * 4;
    const float* gb = gates + (size_t)b * 4 * HH;
    float4 gi = *(const float4*)(gb + j);
    float4 gf = *(const float4*)(gb + HH + j);
    float4 gg = *(const float4*)(gb + 2 * HH + j);
    float4 go = *(const float4*)(gb + 3 * HH + j);
    float4 co = first_c ? make_float4(0.f, 0.f, 0.f, 0.f)
                        : *(const float4*)(c_rd + (size_t)b * HH + j);
    float4 cn, hn;
#define DO_LSTM(X)                                \
    {                                             \
        float iv = sigm(gi.X);                    \
        float fv = sigm(gf.X);                    \
        float gv = tanhf(gg.X);                   \
        float ov = sigm(go.X);                    \
        float c2 = fv * co.X + iv * gv;           \
        cn.X = c2;                                \
        hn.X = ov * tanhf(c2);                    \
    }
    DO_LSTM(x) DO_LSTM(y) DO_LSTM(z) DO_LSTM(w)
#undef DO_LSTM
    if (writer) {
        *(float4*)(c_wr + (size_t)b * HH + j) = cn;
        *(float4*)(h_buf + (size_t)b * HH + j) = hn;
        *(float4*)(Hall_t + (size_t)b * HH + j) = hn;
    }
    if (h_s) *(float4*)(h_s + j) = hn;
}

// ---------------------------------------------------------------------------
// gemm_rowtile: OUT[64][NW] over cols n0..n0+NW = A[64][K] @ W[n0..][K]^T.
// 256 threads. lane = output row; 4 waves split K 4-ways (independent LDS
// chunks, NO cross-wave sync in the main loop); final LDS reduce across waves.
// RELU: A element -> relu(A+abias). OUTMODE: 0 store, 1 store+bias1+bias2,
// 2 read-modify-write add (sole writer, plain ops — NO atomics).
// (Functionally proven in round 3.)
// ---------------------------------------------------------------------------
template <int NW, bool RELU, int OUTMODE>
__device__ __forceinline__ void gemm_rowtile(
    const float* __restrict__ A, int lda, const float* __restrict__ abias,
    const float* __restrict__ Wm, int ldw, int n0, int klen,
    const float* __restrict__ bias1, const float* __restrict__ bias2,
    float* __restrict__ outp, int ldo, float* __restrict__ smem)
{
    static_assert(NW % 8 == 0, "NW multiple of 8");
    constexpr int NWP = NW + 4;  // 16B-aligned row stride for Ws
    const int tid = threadIdx.x;
    const int wv = tid >> 6, lane = tid & 63;
    const int kw = klen >> 2;        // per-wave K extent
    const int kbase = wv * kw;
    const int nch = kw >> 5;         // 32-wide chunks
    float* Asw = smem + wv * (64 * 33);                    // [64][33] per wave
    float* Wsw = smem + 4 * 64 * 33 + wv * (32 * NWP);     // [32][NWP] per wave
    const int arow = lane >> 3, ac4 = lane & 7;
    float acc[NW];
#pragma unroll
    for (int j = 0; j < NW; ++j) acc[j] = 0.f;

    float4 pa[8];
    float4 pw[NW / 8];
    {
        const int kk = kbase + ac4 * 4;
#pragma unroll
        for (int i = 0; i < 8; ++i)
            pa[i] = *(const float4*)(A + (size_t)(i * 8 + arow) * lda + kk);
#pragma unroll
        for (int i = 0; i < NW / 8; ++i)
            pw[i] = *(const float4*)(Wm + (size_t)(n0 + i * 8 + arow) * ldw + kk);
    }
    for (int ch = 0; ch < nch; ++ch) {
        const int kk = kbase + ch * 32;
        float4 bv;
        if (RELU) bv = *(const float4*)(abias + kk + ac4 * 4);
#pragma unroll
        for (int i = 0; i < 8; ++i) {
            float4 v = pa[i];
            if (RELU) {
                v.x = fmaxf(v.x + bv.x, 0.f); v.y = fmaxf(v.y + bv.y, 0.f);
                v.z = fmaxf(v.z + bv.z, 0.f); v.w = fmaxf(v.w + bv.w, 0.f);
            }
            const int base = (i * 8 + arow) * 33 + ac4 * 4;
            Asw[base + 0] = v.x; Asw[base + 1] = v.y;
            Asw[base + 2] = v.z; Asw[base + 3] = v.w;
        }
#pragma unroll
        for (int i = 0; i < NW / 8; ++i) {
            const int r = i * 8 + arow;
            Wsw[(ac4 * 4 + 0) * NWP + r] = pw[i].x;
            Wsw[(ac4 * 4 + 1) * NWP + r] = pw[i].y;
            Wsw[(ac4 * 4 + 2) * NWP + r] = pw[i].z;
            Wsw[(ac4 * 4 + 3) * NWP + r] = pw[i].w;
        }
        if (ch + 1 < nch) {  // register prefetch of next chunk
            const int k2 = kbase + (ch + 1) * 32 + ac4 * 4;
#pragma unroll
            for (int i = 0; i < 8; ++i)
                pa[i] = *(const float4*)(A + (size_t)(i * 8 + arow) * lda + k2);
#pragma unroll
            for (int i = 0; i < NW / 8; ++i)
                pw[i] = *(const float4*)(Wm + (size_t)(n0 + i * 8 + arow) * ldw + k2);
        }
#pragma unroll
        for (int k = 0; k < 32; ++k) {
            const float a = Asw[lane * 33 + k];  // (lane+k)%32: conflict-free
#pragma unroll
            for (int j4 = 0; j4 < NW / 4; ++j4) {
                const float4 w4 = *(const float4*)&Wsw[k * NWP + j4 * 4];
                acc[j4 * 4 + 0] += a * w4.x;
                acc[j4 * 4 + 1] += a * w4.y;
                acc[j4 * 4 + 2] += a * w4.z;
                acc[j4 * 4 + 3] += a * w4.w;
            }
        }
    }
    // cross-wave reduce (red aliases As region: sync before overwrite)
    __syncthreads();
    float* red = smem;  // [4][64][NW]
#pragma unroll
    for (int j4 = 0; j4 < NW / 4; ++j4)
        *(float4*)&red[((wv * 64 + lane) * NW) + j4 * 4] = make_float4(
            acc[j4 * 4 + 0], acc[j4 * 4 + 1], acc[j4 * 4 + 2], acc[j4 * 4 + 3]);
    __syncthreads();
    constexpr int P = NW / 4;
    const int row = tid >> 2, jg = (tid & 3) * P;
#pragma unroll
    for (int p = 0; p < P; ++p) {
        const int j = jg + p;
        float v = red[(0 * 64 + row) * NW + j] + red[(1 * 64 + row) * NW + j] +
                  red[(2 * 64 + row) * NW + j] + red[(3 * 64 + row) * NW + j];
        if (OUTMODE == 1) v += bias1[n0 + j] + bias2[n0 + j];
        if (OUTMODE == 2)
            outp[(size_t)row * ldo + n0 + j] += v;
        else
            outp[(size_t)row * ldo + n0 + j] = v;
    }
    __syncthreads();  // protect smem before next phase reuses it
}

// ---------------------------------------------------------------------------
// k_loop: 128-step recurrence, 3 grid barriers per step, ZERO data atomics,
// ALL 256 blocks busy in EVERY phase (round-3 imbalance fix).
// Phase A' (blocks = (b,hq)): LSTM(t-1) recompute x4 + ALL 256 scores
//          (16 parallel 16-lane groups x 16 serial l) + softmax (redundant)
//          + ctx quarter (hq).
// Phase B: blocks 0..127 comb (x_acc = xin@Wcomb^T, NW=8);
//          blocks 128..255 gates = h@Whh^T + b_ih + b_hh (NW=32).
// Phase C: all 256 blocks: gates += relu(x_acc+b_comb)@Wih^T (NW=16, RMW).
// ---------------------------------------------------------------------------
__global__ __launch_bounds__(256) void k_loop(
    const int* __restrict__ tok_all, const float* __restrict__ enc,
    const float* __restrict__ encT, const float* __restrict__ emb,
    const float* __restrict__ Wattn, const float* __restrict__ battn,
    const float* __restrict__ Wcomb, const float* __restrict__ bcomb,
    const float* __restrict__ Wih, const float* __restrict__ Whh,
    const float* __restrict__ b_ih, const float* __restrict__ b_hh,
    float* __restrict__ Hall, float* __restrict__ xin,
    float* __restrict__ x_acc, float* __restrict__ gates,
    float* __restrict__ h_buf, float* __restrict__ c0, float* __restrict__ c1,
    unsigned* __restrict__ bar, int use_t)
{
    __shared__ __align__(16) float smem[4 * 64 * 33 + 4 * 32 * 36];  // 52.2 KB
    const int bid = blockIdx.x;
    const int tid = threadIdx.x;
    const int w = tid >> 6, lane = tid & 63;

    const int is64 = (tok_all[1] == 0 && tok_all[3] == 0 && tok_all[5] == 0 &&
                      tok_all[7] == 0);

    for (int t = 0; t < TT; ++t) {
        // ========== Phase A': LSTM + scores + softmax + ctx quarter ========
        {
            const int b = bid >> 2, hq = bid & 3;
            float* e_s = smem;                    // [1024]
            float* h_s = smem + HH;               // [1024]
            float* sc = smem + 2 * HH;            // [256]
            float* red = sc + LL;                 // [16]
            float4* part_s = (float4*)(red + 16); // [4][64] float4

            const int tok = is64 ? tok_all[2 * (b * TT + t)] : tok_all[b * TT + t];
            float4 ev = ((const float4*)(emb + (size_t)tok * HH))[tid];
            ((float4*)e_s)[tid] = ev;
            if (hq == 0) ((float4*)(xin + (size_t)b * 2 * HH))[tid] = ev;

            if (t == 0) {
                float4 hv = ((const float4*)(enc + (size_t)(LL - 1) * BB * HH +
                                             (size_t)b * HH))[tid];
                ((float4*)h_s)[tid] = hv;
                if (hq == 0) ((float4*)(h_buf + (size_t)b * HH))[tid] = hv;
            } else {
                lstm_pb(gates, (t & 1) ? c1 : c0, (t & 1) ? c0 : c1, h_buf,
                        Hall + (size_t)(t - 1) * BB * HH, h_s, b, tid, t == 1,
                        hq == 0);
            }
            __syncthreads();

            // scores: 16 parallel (wave, 16-lane-group) streams x 16 serial l
            const float4* xs4 = (const float4*)smem;  // [e|h] = 512 float4
            const int g16 = lane >> 4, sub = lane & 15;
            for (int i = 0; i < 16; ++i) {
                const int l = w * 64 + i * 4 + g16;
                const float4* wr = (const float4*)(Wattn + (size_t)l * 2 * HH);
                float a = 0.f;
#pragma unroll
                for (int it = 0; it < 32; ++it) {
                    float4 wv = wr[it * 16 + sub];
                    float4 xv = xs4[it * 16 + sub];
                    a += wv.x * xv.x + wv.y * xv.y + wv.z * xv.z + wv.w * xv.w;
                }
                a += __shfl_down(a, 8, 16);
                a += __shfl_down(a, 4, 16);
                a += __shfl_down(a, 2, 16);
                a += __shfl_down(a, 1, 16);
                if (sub == 0) sc[l] = a + battn[l];
            }
            __syncthreads();

            // softmax over sc[256] (one element per thread; redundant per hq)
            const float sv = sc[tid];
            float m = sv;
#pragma unroll
            for (int o = 32; o > 0; o >>= 1) m = fmaxf(m, __shfl_down(m, o, 64));
            if (lane == 0) red[w] = m;
            __syncthreads();
            m = fmaxf(fmaxf(red[0], red[1]), fmaxf(red[2], red[3]));
            const float ex = expf(sv - m);
            float s = ex;
#pragma unroll
            for (int o = 32; o > 0; o >>= 1) s += __shfl_down(s, o, 64);
            if (lane == 0) red[4 + w] = s;
            __syncthreads();
            const float tot = red[4] + red[5] + red[6] + red[7];
            sc[tid] = ex / tot;
            __syncthreads();

            // ctx quarter: float4 col index col4 = hq*64+lane in [0,256);
            // wave w sums l in [w*64,w*64+64); cross-wave reduce via LDS.
            const int col4 = hq * 64 + lane;
            const float4* ebase;
            size_t lstr;
            if (use_t) {  // contiguous per-b stream [b][l][h]
                ebase = (const float4*)(encT + (size_t)b * LL * HH) + col4;
                lstr = HH / 4;
            } else {
                ebase = (const float4*)(enc + (size_t)b * HH) + col4;
                lstr = (size_t)BB * HH / 4;
            }
            float4 cacc = make_float4(0.f, 0.f, 0.f, 0.f);
#pragma unroll 8
            for (int li = 0; li < 64; ++li) {
                const int l = w * 64 + li;
                const float a = sc[l];
                float4 e2 = ebase[(size_t)l * lstr];
                cacc.x += a * e2.x; cacc.y += a * e2.y;
                cacc.z += a * e2.z; cacc.w += a * e2.w;
            }
            part_s[w * 64 + lane] = cacc;
            __syncthreads();
            if (w == 0) {
                float4 p0 = part_s[lane];
                float4 p1 = part_s[64 + lane];
                float4 p2 = part_s[128 + lane];
                float4 p3 = part_s[192 + lane];
                float4 r4;
                r4.x = p0.x + p1.x + p2.x + p3.x;
                r4.y = p0.y + p1.y + p2.y + p3.y;
                r4.z = p0.z + p1.z + p2.z + p3.z;
                r4.w = p0.w + p1.w + p2.w + p3.w;
                ((float4*)(xin + (size_t)b * 2 * HH + HH))[col4] = r4;
            }
        }
        grid_barrier(bar);

        // ================= Phase B: comb || h@Whh^T+biases =================
        if (bid < 128) {
            gemm_rowtile<8, false, 0>(xin, 2 * HH, nullptr, Wcomb, 2 * HH,
                                      bid * 8, 2 * HH, nullptr, nullptr, x_acc,
                                      HH, smem);
        } else {
            gemm_rowtile<32, false, 1>(h_buf, HH, nullptr, Whh, HH,
                                       (bid - 128) * 32, HH, b_ih, b_hh, gates,
                                       4 * HH, smem);
        }
        grid_barrier(bar);

        // ================= Phase C: gates += relu(x+b)@Wih^T ===============
        gemm_rowtile<16, true, 2>(x_acc, HH, bcomb, Wih, HH, bid * 16, HH,
                                  nullptr, nullptr, gates, 4 * HH, smem);
        grid_barrier(bar);
    }

    // ================= Epilogue: final LSTM -> Hall[T-1] ===================
    if (bid < BB) {
        lstm_pb(gates, (TT & 1) ? c1 : c0, (TT & 1) ? c0 : c1, h_buf,
                Hall + (size_t)(TT - 1) * BB * HH, nullptr, bid, tid, false,
                true);
    }
}

// ---------------------------------------------------------------------------
// k_tr: one-time enc [L][B][H] -> encT [B][L][H] (both sides coalesced).
// ---------------------------------------------------------------------------
__global__ __launch_bounds__(256) void k_tr(const float* __restrict__ enc,
                                            float* __restrict__ encT)
{
    const size_t idx = (size_t)blockIdx.x * 256 + threadIdx.x;  // float4 index
    const int h4 = idx & 255;
    const size_t lb = idx >> 8;
    const int b = lb & 63;
    const int l = (int)(lb >> 6);
    ((float4*)encT)[(((size_t)b * LL + l) * (HH / 4)) + h4] =
        ((const float4*)enc)[idx];
}

// ---------------------------------------------------------------------------
// k_out: out[t,b,v] = logits - LSE over b (log_softmax over BATCH axis).
// Unchanged (proven). b_out cancels in log-softmax over batch.
// ---------------------------------------------------------------------------
__global__ __launch_bounds__(256) void k_out(const float* __restrict__ Hall,
                                             const float* __restrict__ Wout,
                                             float* __restrict__ out)
{
    const int t = blockIdx.y;
    const int n0 = blockIdx.x * 128;
    const float* A = Hall + (size_t)t * BB * HH;
    __shared__ float As[32][68];
    __shared__ float Ws[32][132];
    __shared__ float Cs[64][129];
    __shared__ float lse_s[128];
    const int tid = threadIdx.x;
    const int ty = tid >> 4, tx = tid & 15;
    const int q = tid & 7, r = tid >> 3;
    float acc[4][8] = {};

    float4 pa0, pa1, pw0, pw1, pw2, pw3;
    {
        const int kk = q * 4;
        pa0 = *(const float4*)(A + (size_t)r * HH + kk);
        pa1 = *(const float4*)(A + (size_t)(r + 32) * HH + kk);
        pw0 = *(const float4*)(Wout + (size_t)(n0 + r) * HH + kk);
        pw1 = *(const float4*)(Wout + (size_t)(n0 + r + 32) * HH + kk);
        pw2 = *(const float4*)(Wout + (size_t)(n0 + r + 64) * HH + kk);
        pw3 = *(const float4*)(Wout + (size_t)(n0 + r + 96) * HH + kk);
    }
    for (int kc = 0; kc < HH; kc += 32) {
        As[q * 4 + 0][r] = pa0.x; As[q * 4 + 1][r] = pa0.y;
        As[q * 4 + 2][r] = pa0.z; As[q * 4 + 3][r] = pa0.w;
        As[q * 4 + 0][r + 32] = pa1.x; As[q * 4 + 1][r + 32] = pa1.y;
        As[q * 4 + 2][r + 32] = pa1.z; As[q * 4 + 3][r + 32] = pa1.w;
        Ws[q * 4 + 0][r] = pw0.x; Ws[q * 4 + 1][r] = pw0.y;
        Ws[q * 4 + 2][r] = pw0.z; Ws[q * 4 + 3][r] = pw0.w;
        Ws[q * 4 + 0][r + 32] = pw1.x; Ws[q * 4 + 1][r + 32] = pw1.y;
        Ws[q * 4 + 2][r + 32] = pw1.z; Ws[q * 4 + 3][r + 32] = pw1.w;
        Ws[q * 4 + 0][r + 64] = pw2.x; Ws[q * 4 + 1][r + 64] = pw2.y;
        Ws[q * 4 + 2][r + 64] = pw2.z; Ws[q * 4 + 3][r + 64] = pw2.w;
        Ws[q * 4 + 0][r + 96] = pw3.x; Ws[q * 4 + 1][r + 96] = pw3.y;
        Ws[q * 4 + 2][r + 96] = pw3.z; Ws[q * 4 + 3][r + 96] = pw3.w;
        __syncthreads();
        if (kc + 32 < HH) {
            const int kk = kc + 32 + q * 4;
            pa0 = *(const float4*)(A + (size_t)r * HH + kk);
            pa1 = *(const float4*)(A + (size_t)(r + 32) * HH + kk);
            pw0 = *(const float4*)(Wout + (size_t)(n0 + r) * HH + kk);
            pw1 = *(const float4*)(Wout + (size_t)(n0 + r + 32) * HH + kk);
            pw2 = *(const float4*)(Wout + (size_t)(n0 + r + 64) * HH + kk);
            pw3 = *(const float4*)(Wout + (size_t)(n0 + r + 96) * HH + kk);
        }
#pragma unroll
        for (int k = 0; k < 32; ++k) {
            const float4 a = *(const float4*)&As[k][ty * 4];
            const float4 w0 = *(const float4*)&Ws[k][tx * 8];
            const float4 w1 = *(const float4*)&Ws[k][tx * 8 + 4];
            const float av[4] = {a.x, a.y, a.z, a.w};
            const float bv[8] = {w0.x, w0.y, w0.z, w0.w, w1.x, w1.y, w1.z, w1.w};
#pragma unroll
            for (int i = 0; i < 4; ++i)
#pragma unroll
                for (int j = 0; j < 8; ++j) acc[i][j] += av[i] * bv[j];
        }
        __syncthreads();
    }
#pragma unroll
    for (int i = 0; i < 4; ++i)
#pragma unroll
        for (int j = 0; j < 8; ++j) Cs[ty * 4 + i][tx * 8 + j] = acc[i][j];
    __syncthreads();

    if (tid < 128) {
        float m = -1e30f;
        for (int b = 0; b < 64; ++b) m = fmaxf(m, Cs[b][tid]);
        float s = 0.f;
        for (int b = 0; b < 64; ++b) s += expf(Cs[b][tid] - m);
        lse_s[tid] = m + logf(s);
    }
    __syncthreads();

    const int col = tid & 127, bh = tid >> 7;
    float* outp = out + (size_t)t * BB * VV + n0 + col;
    for (int b = bh; b < 64; b += 2)
        outp[(size_t)b * VV] = Cs[b][col] - lse_s[col];
}

// ---------------------------------------------------------------------------
extern "C" void kernel_launch(void* const* d_in, const int* in_sizes, int n_in,
                              void* d_out, int out_size, void* d_ws, size_t ws_size,
                              hipStream_t stream)
{
    const int* tok = (const int*)d_in[0];
    const float* enc = (const float*)d_in[1];
    const float* emb = (const float*)d_in[2];
    const float* W_attn = (const float*)d_in[3];
    const float* b_attn = (const float*)d_in[4];
    const float* W_comb = (const float*)d_in[5];
    const float* b_comb = (const float*)d_in[6];
    const float* W_ih = (const float*)d_in[7];
    const float* W_hh = (const float*)d_in[8];
    const float* b_ih = (const float*)d_in[9];
    const float* b_hh = (const float*)d_in[10];
    const float* W_out = (const float*)d_in[11];
    // d_in[12] = b_out: cancels in log_softmax(axis=batch)
    float* out = (float*)d_out;
    float* ws = (float*)d_ws;

    const size_t n_Hall = (size_t)TT * BB * HH;   // 8388608
    const size_t n_xin = (size_t)BB * 2 * HH;     // 131072
    const size_t n_xacc = (size_t)BB * HH;        // 65536
    const size_t n_gates = (size_t)BB * 4 * HH;   // 262144
    const size_t n_bh = (size_t)BB * HH;          // h, c0, c1 each
    const size_t n_bar = 2048;
    const size_t n_encT = (size_t)BB * LL * HH;   // 16777216 (optional)
    const size_t base =
        n_Hall + n_xin + n_xacc + n_gates + 3 * n_bh + n_bar;
    if (ws_size < base * 4) return;  // would corrupt; bail
    const int use_t = (ws_size >= (base + n_encT) * 4) ? 1 : 0;

    float* H_all = ws;
    float* xin = H_all + n_Hall;
    float* x_acc = xin + n_xin;
    float* gates = x_acc + n_xacc;
    float* h_buf = gates + n_gates;
    float* c0 = h_buf + n_bh;
    float* c1 = c0 + n_bh;
    unsigned* bar = (unsigned*)(c1 + n_bh);
    float* encT = (float*)(bar + n_bar);

    hipMemsetAsync(bar, 0, n_bar * 4, stream);
    if (use_t)
        k_tr<<<(LL * BB * HH / 4) / 256, 256, 0, stream>>>(enc, encT);

    k_loop<<<NBLK, 256, 0, stream>>>(tok, enc, encT, emb, W_attn, b_attn,
                                     W_comb, b_comb, W_ih, W_hh, b_ih, b_hh,
                                     H_all, xin, x_acc, gates, h_buf, c0, c1,
                                     bar, use_t);
    k_out<<<dim3(125, 128), 256, 0, stream>>>(H_all, W_out, out);
}